// Round 21
// baseline (122.829 us; speedup 1.0000x reference)
//
#include <hip/hip_runtime.h>
#include <float.h>

#define NT 32768
#define DIM 2048
#define NE 64
#define TAU 1e-3f
#define CHUNK 64
#define NCH (DIM / CHUNK)   // 32 chunks

typedef __attribute__((ext_vector_type(8))) short short8;
typedef __attribute__((ext_vector_type(4))) float f32x4;
typedef const __attribute__((address_space(1))) void gas_void;
typedef __attribute__((address_space(3))) void las_void;

__device__ __forceinline__ unsigned short f2bf(float f) {
    unsigned u = __float_as_uint(f);
    u += 0x7fffu + ((u >> 16) & 1u);          // RNE
    return (unsigned short)(u >> 16);
}
__device__ __forceinline__ float bf2f(unsigned short h) {
    return __uint_as_float(((unsigned)h) << 16);
}

// Pack gw into MFMA-B fragment order, hi/lo interleaved 32B records:
// wpk[((et*64 + ksg)*64 + lane)*16 + {0..7 hi, 8..15 lo}]
//   = split of gw[et*16 + (lane&15)][ksg*32 + (lane>>4)*8 + j]
__global__ __launch_bounds__(256)
void prep_w(const float* __restrict__ gw, unsigned short* __restrict__ wpk,
            int* __restrict__ cnt) {
    const int gid  = blockIdx.x * 256 + threadIdx.x;   // 16384 threads
    const int lane = gid & 63;
    const int ksg  = (gid >> 6) & 63;
    const int et   = gid >> 12;
    const int e    = et * 16 + (lane & 15);
    const int k0   = ksg * 32 + (lane >> 4) * 8;

    float4 v0 = *(const float4*)(gw + (size_t)e * DIM + k0);
    float4 v1 = *(const float4*)(gw + (size_t)e * DIM + k0 + 4);
    float xf[8] = {v0.x, v0.y, v0.z, v0.w, v1.x, v1.y, v1.z, v1.w};
    short8 h, l;
#pragma unroll
    for (int j = 0; j < 8; ++j) {
        unsigned short hh = f2bf(xf[j]);
        h[j] = (short)hh;
        l[j] = (short)f2bf(xf[j] - bf2f(hh));
    }
    *(short8*)(wpk + (size_t)gid * 16)     = h;
    *(short8*)(wpk + (size_t)gid * 16 + 8) = l;
    if (gid == 0) *cnt = 0;
}

// One wave per block: 16 tokens x 64 experts. A staged via global_load_lds
// (wave-private dbuf, swizzled SOURCE address, linear LDS dest). NO barriers.
__global__ __launch_bounds__(64, 3)
void router_mfma(const float* __restrict__ x,
                 const unsigned short* __restrict__ wpk,
                 float* __restrict__ out,
                 int* __restrict__ cnt, int* __restrict__ list) {
    __shared__ __align__(16) unsigned char smem[8192];   // 2 bufs x 4KB fp32

    const int lane = threadIdx.x & 63;
    const int t0   = blockIdx.x * 16;

    // staging source (swizzled global): issue i, lane l -> row 4i+(l>>4),
    // LDS slot q'=l&15 receives global quad q = q' ^ (row&7)
    const float* gs[4];
#pragma unroll
    for (int i = 0; i < 4; ++i) {
        const int rw = 4 * i + (lane >> 4);
        const int q  = (lane & 15) ^ (rw & 7);
        gs[i] = x + (size_t)(t0 + rw) * DIM + q * 4;
    }

    // compute-side swizzled LDS read offsets: row r=lane&15, quad kg=lane>>4
    const int r  = lane & 15;
    const int kg = lane >> 4;
    unsigned aoff[2][2];
#pragma unroll
    for (int ks = 0; ks < 2; ++ks)
#pragma unroll
        for (int j = 0; j < 2; ++j)
            aoff[ks][j] = (unsigned)(r * 256 + (((ks * 8 + kg * 2 + j) ^ (r & 7)) << 4));

    // B pointers: 4 expert-tiles; record = 32B (hi 16B | lo 16B)
    const unsigned short* wp0 = wpk + (size_t)lane * 16;
    const unsigned short* wp1 = wp0 + 65536;
    const unsigned short* wp2 = wp0 + 131072;
    const unsigned short* wp3 = wp0 + 196608;

    f32x4 accP[4], accQ[4];
#pragma unroll
    for (int et = 0; et < 4; ++et)
#pragma unroll
        for (int j = 0; j < 4; ++j) { accP[et][j] = 0.f; accQ[et][j] = 0.f; }

    short8 Bh0[4], Bl0[4], Bh1[4], Bl1[4];

#define STAGE(buf_, c_) { _Pragma("unroll") for (int i = 0; i < 4; ++i) { \
        __builtin_amdgcn_global_load_lds( \
            (gas_void*)(gs[i] + (size_t)(c_) * CHUNK), \
            (las_void*)(smem + (buf_) * 4096 + i * 1024), 16, 0, 0); } }

#define BLOADK(bk_, c_, ks_) { \
        const size_t o_ = (size_t)((c_) * 2 + (ks_)) * 1024; \
        Bh##bk_[0] = *(const short8*)(wp0 + o_); Bl##bk_[0] = *(const short8*)(wp0 + o_ + 8); \
        Bh##bk_[1] = *(const short8*)(wp1 + o_); Bl##bk_[1] = *(const short8*)(wp1 + o_ + 8); \
        Bh##bk_[2] = *(const short8*)(wp2 + o_); Bl##bk_[2] = *(const short8*)(wp2 + o_ + 8); \
        Bh##bk_[3] = *(const short8*)(wp3 + o_); Bl##bk_[3] = *(const short8*)(wp3 + o_ + 8); }

// truncation split + 12 MFMA (R18-proven math)
#define SPLIT_MFMA(v0_, v1_, bk_) { \
        float f_[8] = {v0_.x, v0_.y, v0_.z, v0_.w, v1_.x, v1_.y, v1_.z, v1_.w}; \
        short8 Ah_, Al_; \
        _Pragma("unroll") for (int j = 0; j < 8; ++j) { \
            unsigned u_ = __float_as_uint(f_[j]); \
            Ah_[j] = (short)(unsigned short)(u_ >> 16); \
            float lo_ = f_[j] - __uint_as_float(u_ & 0xffff0000u); \
            Al_[j] = (short)(unsigned short)(__float_as_uint(lo_) >> 16); } \
        _Pragma("unroll") for (int et = 0; et < 4; ++et) { \
            accP[et] = __builtin_amdgcn_mfma_f32_16x16x32_bf16(Ah_, Bh##bk_[et], accP[et], 0, 0, 0); \
            accQ[et] = __builtin_amdgcn_mfma_f32_16x16x32_bf16(Ah_, Bl##bk_[et], accQ[et], 0, 0, 0); \
            accQ[et] = __builtin_amdgcn_mfma_f32_16x16x32_bf16(Al_, Bh##bk_[et], accQ[et], 0, 0, 0); } }

    // prologue: chunk 0 DMA in flight
    STAGE(0, 0)

    // K loop, NO barriers. FIFO vmcnt: [stage(c) 4][B0 8][B1 8] -> vmcnt(16)
    // drains exactly stage(c) (oldest); STAGE(c+1) issued after B1 so the
    // compiler's B-use waits (vmcnt 12/4) never drain it.
#pragma unroll 1
    for (int c = 0; c < NCH - 1; ++c) {
        const int cur = c & 1;
        BLOADK(0, c, 0)
        BLOADK(1, c, 1)
        asm volatile("s_waitcnt vmcnt(16)" ::: "memory");
        __builtin_amdgcn_sched_barrier(0);
        float4 a00 = *(const float4*)(smem + cur * 4096 + aoff[0][0]);
        float4 a01 = *(const float4*)(smem + cur * 4096 + aoff[0][1]);
        float4 a10 = *(const float4*)(smem + cur * 4096 + aoff[1][0]);
        float4 a11 = *(const float4*)(smem + cur * 4096 + aoff[1][1]);
        STAGE(cur ^ 1, c + 1)
        SPLIT_MFMA(a00, a01, 0)
        SPLIT_MFMA(a10, a11, 1)
    }
    // tail c = 31: no further STAGE
    {
        const int cur = (NCH - 1) & 1;
        BLOADK(0, NCH - 1, 0)
        BLOADK(1, NCH - 1, 1)
        asm volatile("s_waitcnt vmcnt(16)" ::: "memory");
        __builtin_amdgcn_sched_barrier(0);
        float4 a00 = *(const float4*)(smem + cur * 4096 + aoff[0][0]);
        float4 a01 = *(const float4*)(smem + cur * 4096 + aoff[0][1]);
        float4 a10 = *(const float4*)(smem + cur * 4096 + aoff[1][0]);
        float4 a11 = *(const float4*)(smem + cur * 4096 + aoff[1][1]);
        SPLIT_MFMA(a00, a01, 0)
        SPLIT_MFMA(a10, a11, 1)
    }

#undef STAGE
#undef BLOADK
#undef SPLIT_MFMA

    // ---- epilogue: fully in-wave (R18-proven). lane holds token
    //      (lane>>4)*4+jr, experts et*16 + (lane&15). ----
    float* mout = out;
    float* wout = out + (size_t)NT * NE;
    float* iout = wout + (size_t)NT * 2;
    const int l15 = lane & 15;

#pragma unroll
    for (int jr = 0; jr < 4; ++jr) {
        const int tok = t0 + (lane >> 4) * 4 + jr;

        float m1 = -FLT_MAX, m2 = -FLT_MAX, m3 = -FLT_MAX;
        int   i1 = NE, i2 = NE, i3 = NE;
        auto ins = [&](float v, int e) {
            bool b1 = (v > m1) || (v == m1 && e < i1);
            bool b2 = (v > m2) || (v == m2 && e < i2);
            bool b3 = (v > m3) || (v == m3 && e < i3);
            if (b1)      { m3 = m2; i3 = i2; m2 = m1; i2 = i1; m1 = v; i1 = e; }
            else if (b2) { m3 = m2; i3 = i2; m2 = v; i2 = e; }
            else if (b3) { m3 = v; i3 = e; }
        };
        ins(accP[0][jr] + accQ[0][jr], l15);
        ins(accP[1][jr] + accQ[1][jr], 16 + l15);
        ins(accP[2][jr] + accQ[2][jr], 32 + l15);
        ins(accP[3][jr] + accQ[3][jr], 48 + l15);
#pragma unroll
        for (int off = 1; off <= 8; off <<= 1) {   // merge within 16-lane group
            float om1 = __shfl_xor(m1, off, 64); int oi1 = __shfl_xor(i1, off, 64);
            float om2 = __shfl_xor(m2, off, 64); int oi2 = __shfl_xor(i2, off, 64);
            float om3 = __shfl_xor(m3, off, 64); int oi3 = __shfl_xor(i3, off, 64);
            ins(om1, oi1); ins(om2, oi2); ins(om3, oi3);
        }

        float ed  = expf(m2 - m1);
        float inv = 1.f / (1.f + ed);

#pragma unroll
        for (int et = 0; et < 4; ++et) {
            int e = et * 16 + l15;
            mout[(size_t)tok * NE + e] = (e == i1 || e == i2) ? 1.f : 0.f;
        }
        if (l15 == 0) {
            *(float2*)(wout + 2 * tok) = make_float2(inv, ed * inv);
            *(float2*)(iout + 2 * tok) = make_float2((float)i1, (float)i2);
            if ((m1 - m2 < TAU) || (m2 - m3 < TAU)) {
                int slot = atomicAdd(cnt, 1);
                list[slot] = tok;
            }
        }
    }
}

// Exact fp32 recompute of flagged (near-tie) tokens; overwrites their outputs.
__global__ __launch_bounds__(256)
void repair(const float* __restrict__ x, const float* __restrict__ gw,
            float* __restrict__ out, const int* __restrict__ cnt,
            const int* __restrict__ list) {
    __shared__ float red[64][5];
    const int n   = *cnt;
    const int tid = threadIdx.x;
    const int e   = tid & 63, qq = tid >> 6;     // expert, k-quarter

    float* mout = out;
    float* wout = out + (size_t)NT * NE;
    float* iout = wout + (size_t)NT * 2;

    for (int i = blockIdx.x; i < n; i += gridDim.x) {
        const int tok = list[i];
        const float* xr = x + (size_t)tok * DIM + qq * 512;
        const float* wr = gw + (size_t)e * DIM + qq * 512;
        float a = 0.f;
        for (int j = 0; j < 512; j += 4) {
            float4 xv = *(const float4*)(xr + j);
            float4 wv = *(const float4*)(wr + j);
            a = fmaf(xv.x, wv.x, a); a = fmaf(xv.y, wv.y, a);
            a = fmaf(xv.z, wv.z, a); a = fmaf(xv.w, wv.w, a);
        }
        red[e][qq] = a;
        __syncthreads();
        if (tid < 64) {
            float v = ((red[e][0] + red[e][1]) + red[e][2]) + red[e][3];
            float m1 = v, m2 = -FLT_MAX; int i1 = e, i2 = NE;
#pragma unroll
            for (int off = 1; off <= 32; off <<= 1) {
                float om1 = __shfl_xor(m1, off, 64); int oi1 = __shfl_xor(i1, off, 64);
                float om2 = __shfl_xor(m2, off, 64); int oi2 = __shfl_xor(i2, off, 64);
                bool selfFirst = (m1 > om1) || (m1 == om1 && i1 < oi1);
                if (selfFirst) {
                    if (!((m2 > om1) || (m2 == om1 && i2 < oi1))) { m2 = om1; i2 = oi1; }
                } else {
                    bool c = (m1 > om2) || (m1 == om2 && i1 < oi2);
                    if (c) { m2 = m1; i2 = i1; } else { m2 = om2; i2 = oi2; }
                    m1 = om1; i1 = oi1;
                }
            }
            float ed  = expf(m2 - m1);
            float inv = 1.f / (1.f + ed);
            mout[(size_t)tok * NE + e] = (e == i1 || e == i2) ? 1.f : 0.f;
            if (e == 0) {
                *(float2*)(wout + 2 * tok) = make_float2(inv, ed * inv);
                *(float2*)(iout + 2 * tok) = make_float2((float)i1, (float)i2);
            }
        }
        __syncthreads();
    }
}

extern "C" void kernel_launch(void* const* d_in, const int* in_sizes, int n_in,
                              void* d_out, int out_size, void* d_ws, size_t ws_size,
                              hipStream_t stream) {
    const float* x  = (const float*)d_in[0];
    const float* gw = (const float*)d_in[1];
    float* out = (float*)d_out;

    unsigned short* wpk = (unsigned short*)d_ws;         // 512 KB packed hi|lo
    int* cnt  = (int*)(wpk + 262144);                    // 4 B
    int* list = cnt + 1;                                 // 128 KB

    prep_w<<<dim3(64), dim3(256), 0, stream>>>(gw, wpk, cnt);
    router_mfma<<<dim3(NT / 16), dim3(64), 0, stream>>>(x, wpk, out, cnt, list);
    repair<<<dim3(256), dim3(256), 0, stream>>>(x, gw, out, cnt, list);
}